// Round 6
// baseline (523.211 us; speedup 1.0000x reference)
//
#include <hip/hip_runtime.h>
#include <math.h>

#define BN    8
#define NN    1024
#define HH    64
#define ADIM  8
#define STEPS 5
#define K2    2048                 // N*E
#define ROWS  (BN*NN)              // 8192

typedef __attribute__((ext_vector_type(8))) short bf16x8;
typedef __attribute__((ext_vector_type(4))) float f32x4;

__device__ __forceinline__ unsigned short f2bf(float f) {
    unsigned int u = __float_as_uint(f);
    u += 0x7FFF + ((u >> 16) & 1);          // round-to-nearest-even
    return (unsigned short)(u >> 16);
}
__device__ __forceinline__ float bf2f(unsigned short h) {
    return __uint_as_float(((unsigned int)h) << 16);
}
__device__ __forceinline__ float ftanh(float x) {
    float e = __expf(2.f * x);
    return 1.f - 2.f / (e + 1.f);
}

// ---------------- fused pre-kernel: conv_adj | init | prep_pack ----------------
// grid = 10241: [0,8192) adjacency fp32->bf16; [8192,10240) init; 10240 prep.
__global__ __launch_bounds__(256) void pre_kernel(
    const float* __restrict__ adj,
    const float* __restrict__ init_state,
    const float* __restrict__ We, const float* __restrict__ be,
    const float* __restrict__ Wg,
    unsigned short* __restrict__ adjb,
    unsigned short* __restrict__ edge_t,
    float* __restrict__ h_ws,
    unsigned short* __restrict__ wgp,
    unsigned short* __restrict__ wep)
{
    __shared__ float h_lds[4][65];
    int bid = blockIdx.x;
    int t = threadIdx.x;

    if (bid < 8192) {
        // ---- adjacency conversion (coalesced float4 -> ushort4) ----
        int tid = bid * 256 + t;                  // 0..2097151
        #pragma unroll
        for (int i = 0; i < 4; ++i) {
            size_t idx = (size_t)tid + (size_t)i * 2097152;
            float4 v = ((const float4*)adj)[idx];
            ushort4 o;
            o.x = f2bf(v.x); o.y = f2bf(v.y); o.z = f2bf(v.z); o.w = f2bf(v.w);
            ((ushort4*)adjb)[idx] = o;
        }
        return;
    }
    if (bid < 10240) {
        // ---- init: h_ws = initial_state; edge_t = f(initial_state) ----
        int blk = bid - 8192;
        int r = t >> 6, hp = t & 63;
        int row = blk * 4 + r;
        float hv = init_state[(size_t)row * 64 + hp];
        h_ws[(size_t)row * 64 + hp] = hv;
        h_lds[r][hp] = hv;
        __syncthreads();
        int b = row >> 10, n = row & 1023;
        #pragma unroll
        for (int e = 0; e < 2; ++e) {
            float acc = be[hp * 2 + e];
            #pragma unroll 8
            for (int c = 0; c < 64; ++c)
                acc += h_lds[r][c] * We[c * 128 + hp * 2 + e];
            edge_t[((size_t)b * 64 + hp) * K2 + e * NN + n] = f2bf(acc);
        }
        return;
    }
    // ---- prep: Wg/We -> transposed bf16 hi/lo packs ----
    for (int idx = t; idx < 20480; idx += 256) {
        if (idx < 12288) {
            int k = idx >> 6, c = idx & 63;
            float v = Wg[idx];
            unsigned short hi = f2bf(v);
            unsigned short lo = f2bf(v - bf2f(hi));
            wgp[(size_t)c * 192 + k] = hi;
            wgp[(size_t)(64 + c) * 192 + k] = lo;
        } else {
            int u = idx - 12288;
            int k = u >> 7, c = u & 127;
            float v = We[u];
            unsigned short hi = f2bf(v);
            unsigned short lo = f2bf(v - bf2f(hi));
            wep[(size_t)c * 64 + k] = hi;
            wep[(size_t)(128 + c) * 64 + k] = lo;
        }
    }
}

// ---------------- fused step: barrier-free register GEMM + gate + edge/head ----
// grid = 256 = 8 b x 32 row-tiles; 512 threads = 8 waves.
// GEMM: w = dir*4 + rh*2 + kc; NO LDS staging, NO K-loop barriers.
// B (256 KB/batch, read by 32 blocks) comes straight from L2; A from L3.
// mode: 0 = write edge_t for next step; 1 = last step, compute head output.
__global__ __launch_bounds__(512) void step_kernel(
    const unsigned short* __restrict__ adjb,     // [b][n][4096] bf16
    const unsigned short* __restrict__ ein,      // [b][64][2048] bf16
    unsigned short* __restrict__ eout,           // [b][64][2048] bf16
    float* __restrict__ h_ws,
    const unsigned short* __restrict__ wgp,      // [2][64][192]
    const unsigned short* __restrict__ wep,      // [2][128][64]
    const float* __restrict__ bg,
    const float* __restrict__ be,
    const float* __restrict__ ann,
    const float* __restrict__ Wh, const float* __restrict__ bh,
    const float* __restrict__ Wo, const float* __restrict__ bo,
    float* __restrict__ out,
    int mode)
{
    __shared__ __attribute__((aligned(16))) unsigned short Xhi[32][200];    // 12.8 KB
    __shared__ __attribute__((aligned(16))) unsigned short Xlo[32][200];    // 12.8 KB
    __shared__ __attribute__((aligned(16))) float          hf [32][68];     //  8.7 KB
    __shared__ __attribute__((aligned(16))) unsigned short HNhi[32][72];    //  4.6 KB
    __shared__ __attribute__((aligned(16))) unsigned short HNlo[32][72];    //  4.6 KB
    __shared__ __attribute__((aligned(16))) float          red[4][16][68];  // 17.4 KB

    int t  = threadIdx.x;
    int b  = blockIdx.x >> 5;
    int mt = blockIdx.x & 31;
    int n0 = mt * 32;
    size_t hbase = ((size_t)(b * NN + n0)) * 64;

    // ---- load h rows -> X[.][128..191] (hi/lo) + hf ----
    {
        int r = t >> 4, cg = (t & 15) * 4;
        float4 v = *(const float4*)(h_ws + hbase + (size_t)r * 64 + cg);
        float vv[4] = {v.x, v.y, v.z, v.w};
        #pragma unroll
        for (int j = 0; j < 4; ++j) {
            float hv = vv[j];
            unsigned short hi = f2bf(hv), lo = f2bf(hv - bf2f(hi));
            Xhi[r][128 + cg + j] = hi;
            Xlo[r][128 + cg + j] = lo;
            hf[r][cg + j] = hv;
        }
    }

    int lane = t & 63, w = t >> 6, l15 = lane & 15, q = lane >> 4;
    int dir = w >> 2, rh = (w >> 1) & 1, kc = w & 1;

    // per-lane bases: A rows = own n-rows (L3); B rows = edge h-rows (L2-shared)
    const unsigned short* Al = adjb
        + ((size_t)(b * NN + n0 + rh * 16 + l15)) * 4096 + dir * K2 + kc * 1024 + q * 8;
    const unsigned short* Bl = ein
        + ((size_t)b * 64 + l15) * K2 + kc * 1024 + q * 8;

    f32x4 acc[4];
    #pragma unroll
    for (int ct = 0; ct < 4; ++ct) acc[ct] = (f32x4){0.f, 0.f, 0.f, 0.f};

    // ---- barrier-free K-loop: K=1024 per wave, pure register dataflow ----
    #pragma unroll 8
    for (int ks = 0; ks < 32; ++ks) {
        bf16x8 af = *(const bf16x8*)(Al + ks * 32);
        #pragma unroll
        for (int ct = 0; ct < 4; ++ct) {
            bf16x8 bfr = *(const bf16x8*)(Bl + (size_t)ct * 16 * K2 + ks * 32);
            acc[ct] = __builtin_amdgcn_mfma_f32_16x16x32_bf16(af, bfr, acc[ct], 0, 0, 0);
        }
    }

    // ---- reduce kc-pairs via LDS ----
    int gg = w >> 1;                                 // dir*2 + rh
    if (kc == 1) {
        #pragma unroll
        for (int ct = 0; ct < 4; ++ct)
            #pragma unroll
            for (int i = 0; i < 4; ++i)
                red[gg][q * 4 + i][ct * 16 + l15] = acc[ct][i];
    }
    __syncthreads();
    if (kc == 0) {
        #pragma unroll
        for (int ct = 0; ct < 4; ++ct)
            #pragma unroll
            for (int i = 0; i < 4; ++i) {
                float v = acc[ct][i] + red[gg][q * 4 + i][ct * 16 + l15];
                unsigned short hi = f2bf(v), lo = f2bf(v - bf2f(hi));
                int r  = rh * 16 + q * 4 + i;
                int cc2 = dir * 64 + ct * 16 + l15;
                Xhi[r][cc2] = hi;
                Xlo[r][cc2] = lo;
            }
    }
    __syncthreads();

    // ---- gate (MFMA, hi/lo split): wave -> (mg, 16-col tile) ----
    int mg = w & 1, cg16 = w >> 1;
    int arow = mg * 16 + l15;
    int cc = cg16 * 16 + l15;
    const unsigned short* wcol = wgp + (size_t)cc * 192;
    f32x4 as = (f32x4){0.f, 0.f, 0.f, 0.f}, az;

    #pragma unroll
    for (int ks = 0; ks < 4; ++ks) {                 // shared K = 0..127 (a_in|a_out)
        bf16x8 ah = *(const bf16x8*)&Xhi[arow][ks * 32 + q * 8];
        bf16x8 al = *(const bf16x8*)&Xlo[arow][ks * 32 + q * 8];
        const unsigned short* wb = wcol + ks * 32 + q * 8;
        bf16x8 bh2 = *(const bf16x8*)wb;
        bf16x8 bl2 = *(const bf16x8*)(wb + 64 * 192);
        as = __builtin_amdgcn_mfma_f32_16x16x32_bf16(ah, bh2, as, 0, 0, 0);
        as = __builtin_amdgcn_mfma_f32_16x16x32_bf16(ah, bl2, as, 0, 0, 0);
        as = __builtin_amdgcn_mfma_f32_16x16x32_bf16(al, bh2, as, 0, 0, 0);
    }
    az = as;
    #pragma unroll
    for (int ks = 4; ks < 6; ++ks) {                 // z extra: K = 128..191 (h)
        bf16x8 ah = *(const bf16x8*)&Xhi[arow][ks * 32 + q * 8];
        bf16x8 al = *(const bf16x8*)&Xlo[arow][ks * 32 + q * 8];
        const unsigned short* wb = wcol + ks * 32 + q * 8;
        bf16x8 bh2 = *(const bf16x8*)wb;
        bf16x8 bl2 = *(const bf16x8*)(wb + 64 * 192);
        az = __builtin_amdgcn_mfma_f32_16x16x32_bf16(ah, bh2, az, 0, 0, 0);
        az = __builtin_amdgcn_mfma_f32_16x16x32_bf16(ah, bl2, az, 0, 0, 0);
        az = __builtin_amdgcn_mfma_f32_16x16x32_bf16(al, bh2, az, 0, 0, 0);
    }
    __syncthreads();   // all waves done reading h slots before zh overwrite

    float zv[4], hv[4];
    float bgv = bg[cc];
    #pragma unroll
    for (int i = 0; i < 4; ++i) {
        int r = mg * 16 + q * 4 + i;
        float z = 1.f / (1.f + __expf(-(az[i] + bgv)));
        float h = hf[r][cc];
        zv[i] = z; hv[i] = h;
        float zh = z * h;
        unsigned short hi = f2bf(zh), lo = f2bf(zh - bf2f(hi));
        Xhi[r][128 + cc] = hi;
        Xlo[r][128 + cc] = lo;
    }
    __syncthreads();

    #pragma unroll
    for (int ks = 4; ks < 6; ++ks) {                 // ht extra: K = 128..191 (zh)
        bf16x8 ah = *(const bf16x8*)&Xhi[arow][ks * 32 + q * 8];
        bf16x8 al = *(const bf16x8*)&Xlo[arow][ks * 32 + q * 8];
        const unsigned short* wb = wcol + ks * 32 + q * 8;
        bf16x8 bh2 = *(const bf16x8*)wb;
        bf16x8 bl2 = *(const bf16x8*)(wb + 64 * 192);
        as = __builtin_amdgcn_mfma_f32_16x16x32_bf16(ah, bh2, as, 0, 0, 0);
        as = __builtin_amdgcn_mfma_f32_16x16x32_bf16(ah, bl2, as, 0, 0, 0);
        as = __builtin_amdgcn_mfma_f32_16x16x32_bf16(al, bh2, as, 0, 0, 0);
    }

    #pragma unroll
    for (int i = 0; i < 4; ++i) {
        int r = mg * 16 + q * 4 + i;
        float ht = ftanh(as[i] + bgv);
        float z  = zv[i];
        float hn = (1.f - z) * hv[i] + z * ht;
        if (mode == 0) {
            h_ws[hbase + (size_t)r * 64 + cc] = hn;
            unsigned short hi = f2bf(hn), lo = f2bf(hn - bf2f(hi));
            HNhi[r][cc] = hi;
            HNlo[r][cc] = lo;
        } else {
            hf[r][cc] = hn;                          // final h stays in LDS for head
        }
    }
    __syncthreads();

    if (mode == 0) {
        // ---- edge projection (MFMA, hi/lo split), transposed bf16 store ----
        int me = w & 1, cb2 = (w >> 1) * 2;
        int erow = me * 16 + l15;
        f32x4 ae[2];
        ae[0] = ae[1] = (f32x4){0.f, 0.f, 0.f, 0.f};
        #pragma unroll
        for (int ks = 0; ks < 2; ++ks) {
            bf16x8 ah = *(const bf16x8*)&HNhi[erow][ks * 32 + q * 8];
            bf16x8 al = *(const bf16x8*)&HNlo[erow][ks * 32 + q * 8];
            #pragma unroll
            for (int p = 0; p < 2; ++p) {
                int ec = (cb2 + p) * 16 + l15;
                const unsigned short* wb = wep + (size_t)ec * 64 + ks * 32 + q * 8;
                bf16x8 bh2 = *(const bf16x8*)wb;
                bf16x8 bl2 = *(const bf16x8*)(wb + 128 * 64);
                ae[p] = __builtin_amdgcn_mfma_f32_16x16x32_bf16(ah, bh2, ae[p], 0, 0, 0);
                ae[p] = __builtin_amdgcn_mfma_f32_16x16x32_bf16(ah, bl2, ae[p], 0, 0, 0);
                ae[p] = __builtin_amdgcn_mfma_f32_16x16x32_bf16(al, bh2, ae[p], 0, 0, 0);
            }
        }
        #pragma unroll
        for (int p = 0; p < 2; ++p) {
            int ec = (cb2 + p) * 16 + l15;
            float bev = be[ec];
            int hp2 = ec >> 1, e = ec & 1;
            size_t ebase = ((size_t)b * 64 + hp2) * K2 + (size_t)e * NN
                         + n0 + me * 16 + q * 4;
            ushort4 ev;
            ev.x = f2bf(ae[p][0] + bev);
            ev.y = f2bf(ae[p][1] + bev);
            ev.z = f2bf(ae[p][2] + bev);
            ev.w = f2bf(ae[p][3] + bev);
            *(ushort4*)(eout + ebase) = ev;
        }
    } else {
        // ---- head: h in hf; 16 lanes per row, 4 out-cols each ----
        int r = t >> 4, hq = (t & 15) * 4;
        int row = b * NN + n0 + r;
        float av[ADIM];
        #pragma unroll
        for (int j = 0; j < ADIM; ++j) av[j] = ann[(size_t)row * ADIM + j];
        float ac2[4];
        #pragma unroll
        for (int i = 0; i < 4; ++i) ac2[i] = bh[hq + i];
        #pragma unroll 8
        for (int k = 0; k < 64; ++k) {
            float hv2 = hf[r][k];
            float4 wv = *(const float4*)&Wh[k * 64 + hq];
            ac2[0] += hv2 * wv.x; ac2[1] += hv2 * wv.y;
            ac2[2] += hv2 * wv.z; ac2[3] += hv2 * wv.w;
        }
        #pragma unroll
        for (int k = 0; k < ADIM; ++k) {
            float4 wv = *(const float4*)&Wh[(64 + k) * 64 + hq];
            ac2[0] += av[k] * wv.x; ac2[1] += av[k] * wv.y;
            ac2[2] += av[k] * wv.z; ac2[3] += av[k] * wv.w;
        }
        float v = 0.f;
        #pragma unroll
        for (int i = 0; i < 4; ++i)
            v += ftanh(ac2[i]) * Wo[hq + i];
        #pragma unroll
        for (int m = 8; m; m >>= 1) v += __shfl_xor(v, m, 64);
        if ((t & 15) == 0) out[row] = v + bo[0];
    }
}

extern "C" void kernel_launch(void* const* d_in, const int* in_sizes, int n_in,
                              void* d_out, int out_size, void* d_ws, size_t ws_size,
                              hipStream_t stream) {
    const float* init_state = (const float*)d_in[0];
    const float* ann = (const float*)d_in[1];
    const float* adj = (const float*)d_in[2];
    const float* We  = (const float*)d_in[3];
    const float* be  = (const float*)d_in[4];
    const float* Wg  = (const float*)d_in[5];
    const float* bg  = (const float*)d_in[6];
    const float* Wh  = (const float*)d_in[7];
    const float* bh  = (const float*)d_in[8];
    const float* Wo  = (const float*)d_in[9];
    const float* bo  = (const float*)d_in[10];
    float* out = (float*)d_out;

    // ws: adjb 64MB | edge_a 2MB | edge_b 2MB | h_ws 2MB | wgp 48KB | wep 32KB
    char* wsb = (char*)d_ws;
    unsigned short* adjb   = (unsigned short*)wsb;
    unsigned short* edge_a = (unsigned short*)(wsb + 67108864);
    unsigned short* edge_b = (unsigned short*)(wsb + 69206016);
    float*          h_ws   = (float*)(wsb + 71303168);
    unsigned short* wgp    = (unsigned short*)(wsb + 73400320);
    unsigned short* wep    = (unsigned short*)(wsb + 73449472);

    pre_kernel<<<dim3(10241), dim3(256), 0, stream>>>(
        adj, init_state, We, be, Wg, adjb, edge_a, h_ws, wgp, wep);
    for (int s = 0; s < STEPS; ++s) {
        const unsigned short* ein = (s & 1) ? edge_b : edge_a;
        unsigned short* eo        = (s & 1) ? edge_a : edge_b;
        step_kernel<<<dim3(256), dim3(512), 0, stream>>>(
            adjb, ein, eo, h_ws, wgp, wep, bg, be,
            ann, Wh, bh, Wo, bo, out, (s == STEPS - 1) ? 1 : 0);
    }
}

// Round 7
// 377.358 us; speedup vs baseline: 1.3865x; 1.3865x over previous
//
#include <hip/hip_runtime.h>
#include <math.h>

#define BN    8
#define NN    1024
#define HH    64
#define ADIM  8
#define STEPS 5
#define K2    2048                 // N*E
#define ROWS  (BN*NN)              // 8192

typedef __attribute__((ext_vector_type(8))) short bf16x8;
typedef __attribute__((ext_vector_type(4))) float f32x4;

__device__ __forceinline__ unsigned short f2bf(float f) {
    unsigned int u = __float_as_uint(f);
    u += 0x7FFF + ((u >> 16) & 1);          // round-to-nearest-even
    return (unsigned short)(u >> 16);
}
__device__ __forceinline__ float bf2f(unsigned short h) {
    return __uint_as_float(((unsigned int)h) << 16);
}
__device__ __forceinline__ float ftanh(float x) {
    float e = __expf(2.f * x);
    return 1.f - 2.f / (e + 1.f);
}

// lgkm-only barrier: LDS ops drained, global loads stay in flight
__device__ __forceinline__ void lgkm_barrier() {
    asm volatile("s_waitcnt lgkmcnt(0)" ::: "memory");
    __builtin_amdgcn_s_barrier();
    asm volatile("" ::: "memory");
}

// Fragment-major adjacency: adjf[b][dir][KB(64)][NB(64)][l15(16)][k&31(32)] bf16
// One MFMA A-fragment = 64 lanes x 16 B contiguous (1 KB segment).

// ---------------- one-time: adjacency fp32 -> fragment-major bf16 (LDS transpose) --
// block = (b, dir, ng, kg): 16 n-rows x 256 k. Reads 16 KB coalesced (1 KB/row),
// transposes in LDS, writes 8 x 1 KB contiguous bursts.
__global__ __launch_bounds__(256) void conv_adj(
    const float* __restrict__ in, unsigned short* __restrict__ out)
{
    __shared__ unsigned short tl[8][520];    // 8 tiles of 512 shorts + 8 pad
    int bid = blockIdx.x;
    int kg = bid & 7;            // 8 kb per block
    int ng = (bid >> 3) & 63;    // 16-row group
    int d  = (bid >> 9) & 1;
    int b  = bid >> 10;
    int t = threadIdx.x;

    const float* src = in + ((size_t)(b * 1024 + ng * 16)) * 4096 + d * 2048 + kg * 256;
    #pragma unroll
    for (int it = 0; it < 4; ++it) {
        int u = it * 256 + t;                // 0..1023
        int r = u >> 6, c4 = u & 63;         // row, float4-col
        float4 v = *(const float4*)(src + (size_t)r * 4096 + c4 * 4);
        int k = c4 * 4;
        int kb = k >> 5, kk = k & 31;
        ushort4 o;
        o.x = f2bf(v.x); o.y = f2bf(v.y); o.z = f2bf(v.z); o.w = f2bf(v.w);
        *(ushort4*)&tl[kb][r * 32 + kk] = o;
    }
    __syncthreads();

    unsigned short* dst = out + (((size_t)(b * 2 + d) * 64 + kg * 8) * 64 + ng) * 512;
    #pragma unroll
    for (int it = 0; it < 4; ++it) {
        int u = it * 256 + t;                // 0..1023
        int kb = u >> 7, wo = u & 127;       // tile, ushort4 within tile
        *(ushort4*)(dst + (size_t)kb * 32768 + wo * 4) = *(const ushort4*)&tl[kb][wo * 4];
    }
}

// ---------------- one-time: Wg/We -> transposed bf16 hi/lo packs ----------
__global__ __launch_bounds__(256) void prep_pack(
    const float* __restrict__ Wg, const float* __restrict__ We,
    unsigned short* __restrict__ wgp, unsigned short* __restrict__ wep)
{
    int t = blockIdx.x * 256 + threadIdx.x;
    if (t < 12288) {
        int k = t >> 6, c = t & 63;
        float v = Wg[t];
        unsigned short hi = f2bf(v);
        unsigned short lo = f2bf(v - bf2f(hi));
        wgp[(size_t)c * 192 + k] = hi;
        wgp[(size_t)(64 + c) * 192 + k] = lo;
    } else if (t < 20480) {
        int u = t - 12288;
        int k = u >> 7, c = u & 127;
        float v = We[u];
        unsigned short hi = f2bf(v);
        unsigned short lo = f2bf(v - bf2f(hi));
        wep[(size_t)c * 64 + k] = hi;
        wep[(size_t)(128 + c) * 64 + k] = lo;
    }
}

// ---------------- init: h_ws = initial_state; edge_t = f(initial_state) ----------
__global__ __launch_bounds__(256) void init_kernel(
    const float* __restrict__ init_state,
    const float* __restrict__ We, const float* __restrict__ be,
    float* __restrict__ h_ws, unsigned short* __restrict__ edge_t)
{
    __shared__ float h_lds[4][65];
    int t = threadIdx.x;
    int r = t >> 6, hp = t & 63;
    int row = blockIdx.x * 4 + r;
    float hv = init_state[(size_t)row * 64 + hp];
    h_ws[(size_t)row * 64 + hp] = hv;
    h_lds[r][hp] = hv;
    __syncthreads();
    int b = row >> 10, n = row & 1023;
    #pragma unroll
    for (int e = 0; e < 2; ++e) {
        float acc = be[hp * 2 + e];
        #pragma unroll 8
        for (int c = 0; c < 64; ++c)
            acc += h_lds[r][c] * We[c * 128 + hp * 2 + e];
        edge_t[((size_t)b * 64 + hp) * K2 + e * NN + n] = f2bf(acc);
    }
}

// ---------------- fused step: pipelined GEMM (dense A) + gate + edge/head --------
// grid = 256 = 8 b x 32 row-tiles; 512 threads = 8 waves.
// mode: 0 = write edge for next step; 1 = last step, compute head output.
__global__ __launch_bounds__(512) void step_kernel(
    const unsigned short* __restrict__ adjf,     // fragment-major adjacency
    const unsigned short* __restrict__ ein,      // [b][64][2048] bf16
    unsigned short* __restrict__ eout,           // [b][64][2048] bf16
    float* __restrict__ h_ws,
    const unsigned short* __restrict__ wgp,      // [2][64][192]
    const unsigned short* __restrict__ wep,      // [2][128][64]
    const float* __restrict__ bg,
    const float* __restrict__ be,
    const float* __restrict__ ann,
    const float* __restrict__ Wh, const float* __restrict__ bh,
    const float* __restrict__ Wo, const float* __restrict__ bo,
    float* __restrict__ out,
    int mode)
{
    __shared__ __attribute__((aligned(16))) unsigned short Bs[2][64][264];  // 67.6 KB
    __shared__ __attribute__((aligned(16))) unsigned short Xhi[32][200];    // 12.8 KB
    __shared__ __attribute__((aligned(16))) unsigned short Xlo[32][200];    // 12.8 KB
    __shared__ __attribute__((aligned(16))) float          hf [32][68];     //  8.7 KB
    __shared__ __attribute__((aligned(16))) unsigned short HNhi[32][72];    //  4.6 KB
    __shared__ __attribute__((aligned(16))) unsigned short HNlo[32][72];    //  4.6 KB

    int t  = threadIdx.x;
    int b  = blockIdx.x >> 5;
    int mt = blockIdx.x & 31;
    int n0 = mt * 32;
    size_t hbase = ((size_t)(b * NN + n0)) * 64;

    int lane = t & 63, w = t >> 6, l15 = lane & 15, q = lane >> 4;
    int dir = w >> 2, rh = (w >> 1) & 1, kc = w & 1;
    int nb  = mt * 2 + rh;

    // dense fragment base: A(c, ks) = A2 + (c*8 + ks)*32768 shorts
    const unsigned short* A2 = adjf
        + (((size_t)(b * 2 + dir) * 64 + kc * 4) * 64 + nb) * 512 + l15 * 32 + q * 8;

    // staging map (consecutive lanes -> consecutive 16B)
    int srow[4], scol[4];
    const unsigned short* sptr[4];
    #pragma unroll
    for (int i = 0; i < 4; ++i) {
        int u = i * 512 + t;
        srow[i] = u >> 5; scol[i] = (u & 31) * 8;
        sptr[i] = ein + ((size_t)b * 64 + srow[i]) * K2 + scol[i];
    }

    // ---- h load (issue early) ----
    int hr = t >> 4, hcg = (t & 15) * 4;
    float4 hv4 = *(const float4*)(h_ws + hbase + (size_t)hr * 64 + hcg);

    // ---- prologue: issue stage(0), stage(1), A(0), A(1) ----
    uint4 gA[4], gB[4];
    #pragma unroll
    for (int i = 0; i < 4; ++i) gA[i] = *(const uint4*)(sptr[i]);
    #pragma unroll
    for (int i = 0; i < 4; ++i) gB[i] = *(const uint4*)(sptr[i] + 256);
    bf16x8 afA[4], afB[4];
    #pragma unroll
    for (int ks = 0; ks < 4; ++ks)
        afA[ks] = *(const bf16x8*)(A2 + (size_t)ks * 32768);
    #pragma unroll
    for (int ks = 0; ks < 4; ++ks)
        afB[ks] = *(const bf16x8*)(A2 + (size_t)(8 + ks) * 32768);

    // ---- h -> X[.][128..191] (hi/lo) + hf ----
    {
        float vv[4] = {hv4.x, hv4.y, hv4.z, hv4.w};
        #pragma unroll
        for (int j = 0; j < 4; ++j) {
            float hv = vv[j];
            unsigned short hi = f2bf(hv), lo = f2bf(hv - bf2f(hi));
            Xhi[hr][128 + hcg + j] = hi;
            Xlo[hr][128 + hcg + j] = lo;
            hf[hr][hcg + j] = hv;
        }
    }

    #pragma unroll
    for (int i = 0; i < 4; ++i)
        *(uint4*)&Bs[0][srow[i]][scol[i]] = gA[i];
    lgkm_barrier();

    f32x4 acc[4];
    #pragma unroll
    for (int ct = 0; ct < 4; ++ct) acc[ct] = (f32x4){0.f, 0.f, 0.f, 0.f};

    #pragma unroll
    for (int c = 0; c < 8; ++c) {
        const int par = c & 1;
        if (c < 6) {
            #pragma unroll
            for (int i = 0; i < 4; ++i) {
                uint4 v = *(const uint4*)(sptr[i] + (c + 2) * 256);
                if (par == 0) gA[i] = v; else gB[i] = v;
            }
        }
        #pragma unroll
        for (int ks = 0; ks < 4; ++ks) {
            bf16x8 a = (par == 0) ? afA[ks] : afB[ks];
            #pragma unroll
            for (int ct = 0; ct < 4; ++ct) {
                bf16x8 bfr = *(const bf16x8*)&Bs[par][ct * 16 + l15][kc * 128 + ks * 32 + q * 8];
                acc[ct] = __builtin_amdgcn_mfma_f32_16x16x32_bf16(a, bfr, acc[ct], 0, 0, 0);
            }
        }
        if (c < 6) {
            #pragma unroll
            for (int ks = 0; ks < 4; ++ks) {
                bf16x8 v = *(const bf16x8*)(A2 + (size_t)((c + 2) * 8 + ks) * 32768);
                if (par == 0) afA[ks] = v; else afB[ks] = v;
            }
        }
        if (c < 7) {
            #pragma unroll
            for (int i = 0; i < 4; ++i) {
                uint4 v = (par == 0) ? gB[i] : gA[i];
                *(uint4*)&Bs[par ^ 1][srow[i]][scol[i]] = v;
            }
        }
        lgkm_barrier();
    }

    // ---- reduce kc-pairs via LDS (overlaid on dead Bs region) ----
    float (*red)[16][68] = (float (*)[16][68])(&Bs[0][0][0]);
    int gg = w >> 1;                                 // dir*2 + rh
    if (kc == 1) {
        #pragma unroll
        for (int ct = 0; ct < 4; ++ct)
            #pragma unroll
            for (int i = 0; i < 4; ++i)
                red[gg][q * 4 + i][ct * 16 + l15] = acc[ct][i];
    }
    __syncthreads();
    if (kc == 0) {
        #pragma unroll
        for (int ct = 0; ct < 4; ++ct)
            #pragma unroll
            for (int i = 0; i < 4; ++i) {
                float v = acc[ct][i] + red[gg][q * 4 + i][ct * 16 + l15];
                unsigned short hi = f2bf(v), lo = f2bf(v - bf2f(hi));
                int r  = rh * 16 + q * 4 + i;
                int cc2 = dir * 64 + ct * 16 + l15;
                Xhi[r][cc2] = hi;
                Xlo[r][cc2] = lo;
            }
    }
    __syncthreads();

    // ---- gate (MFMA, hi/lo split): wave -> (mg, 16-col tile) ----
    int mg = w & 1, cg16 = w >> 1;
    int arow = mg * 16 + l15;
    int cc = cg16 * 16 + l15;
    const unsigned short* wcol = wgp + (size_t)cc * 192;
    f32x4 as = (f32x4){0.f, 0.f, 0.f, 0.f}, az;

    #pragma unroll
    for (int ks = 0; ks < 4; ++ks) {                 // shared K = 0..127 (a_in|a_out)
        bf16x8 ah = *(const bf16x8*)&Xhi[arow][ks * 32 + q * 8];
        bf16x8 al = *(const bf16x8*)&Xlo[arow][ks * 32 + q * 8];
        const unsigned short* wb = wcol + ks * 32 + q * 8;
        bf16x8 bh2 = *(const bf16x8*)wb;
        bf16x8 bl2 = *(const bf16x8*)(wb + 64 * 192);
        as = __builtin_amdgcn_mfma_f32_16x16x32_bf16(ah, bh2, as, 0, 0, 0);
        as = __builtin_amdgcn_mfma_f32_16x16x32_bf16(ah, bl2, as, 0, 0, 0);
        as = __builtin_amdgcn_mfma_f32_16x16x32_bf16(al, bh2, as, 0, 0, 0);
    }
    az = as;
    #pragma unroll
    for (int ks = 4; ks < 6; ++ks) {                 // z extra: K = 128..191 (h)
        bf16x8 ah = *(const bf16x8*)&Xhi[arow][ks * 32 + q * 8];
        bf16x8 al = *(const bf16x8*)&Xlo[arow][ks * 32 + q * 8];
        const unsigned short* wb = wcol + ks * 32 + q * 8;
        bf16x8 bh2 = *(const bf16x8*)wb;
        bf16x8 bl2 = *(const bf16x8*)(wb + 64 * 192);
        az = __builtin_amdgcn_mfma_f32_16x16x32_bf16(ah, bh2, az, 0, 0, 0);
        az = __builtin_amdgcn_mfma_f32_16x16x32_bf16(ah, bl2, az, 0, 0, 0);
        az = __builtin_amdgcn_mfma_f32_16x16x32_bf16(al, bh2, az, 0, 0, 0);
    }
    __syncthreads();   // all waves done reading h slots before zh overwrite

    float zv[4], hv[4];
    float bgv = bg[cc];
    #pragma unroll
    for (int i = 0; i < 4; ++i) {
        int r = mg * 16 + q * 4 + i;
        float z = 1.f / (1.f + __expf(-(az[i] + bgv)));
        float h = hf[r][cc];
        zv[i] = z; hv[i] = h;
        float zh = z * h;
        unsigned short hi = f2bf(zh), lo = f2bf(zh - bf2f(hi));
        Xhi[r][128 + cc] = hi;
        Xlo[r][128 + cc] = lo;
    }
    __syncthreads();

    #pragma unroll
    for (int ks = 4; ks < 6; ++ks) {                 // ht extra: K = 128..191 (zh)
        bf16x8 ah = *(const bf16x8*)&Xhi[arow][ks * 32 + q * 8];
        bf16x8 al = *(const bf16x8*)&Xlo[arow][ks * 32 + q * 8];
        const unsigned short* wb = wcol + ks * 32 + q * 8;
        bf16x8 bh2 = *(const bf16x8*)wb;
        bf16x8 bl2 = *(const bf16x8*)(wb + 64 * 192);
        as = __builtin_amdgcn_mfma_f32_16x16x32_bf16(ah, bh2, as, 0, 0, 0);
        as = __builtin_amdgcn_mfma_f32_16x16x32_bf16(ah, bl2, as, 0, 0, 0);
        as = __builtin_amdgcn_mfma_f32_16x16x32_bf16(al, bh2, as, 0, 0, 0);
    }

    #pragma unroll
    for (int i = 0; i < 4; ++i) {
        int r = mg * 16 + q * 4 + i;
        float ht = ftanh(as[i] + bgv);
        float z  = zv[i];
        float hn = (1.f - z) * hv[i] + z * ht;
        if (mode == 0) {
            h_ws[hbase + (size_t)r * 64 + cc] = hn;
            unsigned short hi = f2bf(hn), lo = f2bf(hn - bf2f(hi));
            HNhi[r][cc] = hi;
            HNlo[r][cc] = lo;
        } else {
            hf[r][cc] = hn;                          // final h stays in LDS for head
        }
    }
    __syncthreads();

    if (mode == 0) {
        // ---- edge projection (MFMA, hi/lo split), transposed bf16 store ----
        int me = w & 1, cb2 = (w >> 1) * 2;
        int erow = me * 16 + l15;
        f32x4 ae[2];
        ae[0] = ae[1] = (f32x4){0.f, 0.f, 0.f, 0.f};
        #pragma unroll
        for (int ks = 0; ks < 2; ++ks) {
            bf16x8 ah = *(const bf16x8*)&HNhi[erow][ks * 32 + q * 8];
            bf16x8 al = *(const bf16x8*)&HNlo[erow][ks * 32 + q * 8];
            #pragma unroll
            for (int p = 0; p < 2; ++p) {
                int ec = (cb2 + p) * 16 + l15;
                const unsigned short* wb = wep + (size_t)ec * 64 + ks * 32 + q * 8;
                bf16x8 bh2 = *(const bf16x8*)wb;
                bf16x8 bl2 = *(const bf16x8*)(wb + 128 * 64);
                ae[p] = __builtin_amdgcn_mfma_f32_16x16x32_bf16(ah, bh2, ae[p], 0, 0, 0);
                ae[p] = __builtin_amdgcn_mfma_f32_16x16x32_bf16(ah, bl2, ae[p], 0, 0, 0);
                ae[p] = __builtin_amdgcn_mfma_f32_16x16x32_bf16(al, bh2, ae[p], 0, 0, 0);
            }
        }
        #pragma unroll
        for (int p = 0; p < 2; ++p) {
            int ec = (cb2 + p) * 16 + l15;
            float bev = be[ec];
            int hp2 = ec >> 1, e = ec & 1;
            size_t ebase = ((size_t)b * 64 + hp2) * K2 + (size_t)e * NN
                         + n0 + me * 16 + q * 4;
            ushort4 ev;
            ev.x = f2bf(ae[p][0] + bev);
            ev.y = f2bf(ae[p][1] + bev);
            ev.z = f2bf(ae[p][2] + bev);
            ev.w = f2bf(ae[p][3] + bev);
            *(ushort4*)(eout + ebase) = ev;
        }
    } else {
        // ---- head: h in hf; 16 lanes per row, 4 out-cols each ----
        int r = t >> 4, hq = (t & 15) * 4;
        int row = b * NN + n0 + r;
        float av[ADIM];
        #pragma unroll
        for (int j = 0; j < ADIM; ++j) av[j] = ann[(size_t)row * ADIM + j];
        float ac2[4];
        #pragma unroll
        for (int i = 0; i < 4; ++i) ac2[i] = bh[hq + i];
        #pragma unroll 8
        for (int k = 0; k < 64; ++k) {
            float hv2 = hf[r][k];
            float4 wv = *(const float4*)&Wh[k * 64 + hq];
            ac2[0] += hv2 * wv.x; ac2[1] += hv2 * wv.y;
            ac2[2] += hv2 * wv.z; ac2[3] += hv2 * wv.w;
        }
        #pragma unroll
        for (int k = 0; k < ADIM; ++k) {
            float4 wv = *(const float4*)&Wh[(64 + k) * 64 + hq];
            ac2[0] += av[k] * wv.x; ac2[1] += av[k] * wv.y;
            ac2[2] += av[k] * wv.z; ac2[3] += av[k] * wv.w;
        }
        float v = 0.f;
        #pragma unroll
        for (int i = 0; i < 4; ++i)
            v += ftanh(ac2[i]) * Wo[hq + i];
        #pragma unroll
        for (int m = 8; m; m >>= 1) v += __shfl_xor(v, m, 64);
        if ((t & 15) == 0) out[row] = v + bo[0];
    }
}

extern "C" void kernel_launch(void* const* d_in, const int* in_sizes, int n_in,
                              void* d_out, int out_size, void* d_ws, size_t ws_size,
                              hipStream_t stream) {
    const float* init_state = (const float*)d_in[0];
    const float* ann = (const float*)d_in[1];
    const float* adj = (const float*)d_in[2];
    const float* We  = (const float*)d_in[3];
    const float* be  = (const float*)d_in[4];
    const float* Wg  = (const float*)d_in[5];
    const float* bg  = (const float*)d_in[6];
    const float* Wh  = (const float*)d_in[7];
    const float* bh  = (const float*)d_in[8];
    const float* Wo  = (const float*)d_in[9];
    const float* bo  = (const float*)d_in[10];
    float* out = (float*)d_out;

    // ws: adjf 64MB | edge_a 2MB | edge_b 2MB | h_ws 2MB | wgp 48KB | wep 32KB
    char* wsb = (char*)d_ws;
    unsigned short* adjf   = (unsigned short*)wsb;
    unsigned short* edge_a = (unsigned short*)(wsb + 67108864);
    unsigned short* edge_b = (unsigned short*)(wsb + 69206016);
    float*          h_ws   = (float*)(wsb + 71303168);
    unsigned short* wgp    = (unsigned short*)(wsb + 73400320);
    unsigned short* wep    = (unsigned short*)(wsb + 73449472);

    conv_adj<<<dim3(8192), dim3(256), 0, stream>>>(adj, adjf);
    prep_pack<<<dim3(80), dim3(256), 0, stream>>>(Wg, We, wgp, wep);
    init_kernel<<<dim3(ROWS / 4), dim3(256), 0, stream>>>(init_state, We, be, h_ws, edge_a);
    for (int s = 0; s < STEPS; ++s) {
        const unsigned short* ein = (s & 1) ? edge_b : edge_a;
        unsigned short* eo        = (s & 1) ? edge_a : edge_b;
        step_kernel<<<dim3(256), dim3(512), 0, stream>>>(
            adjf, ein, eo, h_ws, wgp, wep, bg, be,
            ann, Wh, bh, Wo, bo, out, (s == STEPS - 1) ? 1 : 0);
    }
}